// Round 12
// baseline (4201.180 us; speedup 1.0000x reference)
//
#include <hip/hip_runtime.h>

#define BATCH 8
#define KSPLIT 8                       // blocks (CUs) per batch
#define NBLK (BATCH * KSPLIT)          // 64 blocks, 1 per CU, all co-resident
#define N 32768
#define NPOINT 2048
#define NT 256                         // threads per block (4 waves = 1/SIMD)
#define NW (NT / 64)                   // 4 waves
#define NSLOT (KSPLIT * NW)            // 32 published wave-keys per iteration
#define QB (N / 2 / KSPLIT)            // f2 elems per block = 2048

typedef __attribute__((ext_vector_type(2))) float f2;

// Multi-CU FPS, round-11: barrier-1-free publish.
// Every WAVE publishes its own key straight to gslot[b][j][k*4+w] (relaxed
// agent store, lane 0) the moment its DPP reduce finishes -- no LDS combine,
// no barrier before publish.  Wave 0 of each block polls all 32 slots
// (lanes 0..31, 4 cache lines, 8 polling waves per batch), reduces via
// quad_perm DPP + 8-readlane scalar tree, writes s_res; ONE barrier;
// everyone reads.  s_res double-buffered (write j+2 ordered after read j
// by barrier j+1).  Key = (dist_bits<<32 | N-idx) != 0 always.
// Max dist + lowest original index on ties (dist >= 0 -> bits monotone).
// Bit-exact numpy semantics: contract off, (xx+yy)+zz order, no FMA.

#define REP8(M)  M(0) M(1) M(2) M(3) M(4) M(5) M(6) M(7)
#define REP8R(M) M(7) M(6) M(5) M(4) M(3) M(2) M(1) M(0)

// one DPP max step: v = max(v, dpp_shift(v)), invalid lanes contribute 0
#define DPP_UMAX(v, ctrl) {                                                  \
    unsigned _t = (unsigned)__builtin_amdgcn_update_dpp(                     \
        0, (int)(v), (ctrl), 0xf, 0xf, true);                                \
    (v) = (v) > _t ? (v) : _t; }

// full wave-64 max of nonneg uint, result uniform via readlane 63
__device__ __forceinline__ unsigned wave_umax(unsigned v) {
    DPP_UMAX(v, 0x111);   // row_shr:1
    DPP_UMAX(v, 0x112);   // row_shr:2
    DPP_UMAX(v, 0x114);   // row_shr:4
    DPP_UMAX(v, 0x118);   // row_shr:8
    DPP_UMAX(v, 0x142);   // row_bcast:15
    DPP_UMAX(v, 0x143);   // row_bcast:31
    return (unsigned)__builtin_amdgcn_readlane((int)v, 63);
}

// u64 max with quad_perm exchange, ctrl compile-time const
#define QP_U64MAX(v, ctrl) {                                                 \
    unsigned _lo = (unsigned)__builtin_amdgcn_update_dpp(                    \
        0, (int)(unsigned)(v), (ctrl), 0xf, 0xf, false);                     \
    unsigned _hi = (unsigned)__builtin_amdgcn_update_dpp(                    \
        0, (int)(unsigned)((v) >> 32), (ctrl), 0xf, 0xf, false);             \
    unsigned long long _p = ((unsigned long long)_hi << 32) | _lo;           \
    (v) = _p > (v) ? _p : (v); }

__device__ __forceinline__ unsigned long long rdlane_u64(unsigned long long v,
                                                         int lane) {
    const unsigned lo = (unsigned)__builtin_amdgcn_readlane(
        (int)(unsigned)v, lane);
    const unsigned hi = (unsigned)__builtin_amdgcn_readlane(
        (int)(unsigned)(v >> 32), lane);
    return ((unsigned long long)hi << 32) | lo;
}

__global__ __attribute__((amdgpu_flat_work_group_size(NT, NT),
                          amdgpu_waves_per_eu(2, 2)))
void fps_kernel(const float* __restrict__ pts_t,        // (B,3,N)
                float* __restrict__ out,                // (B,3,NPOINT)
                unsigned long long* __restrict__ gslot) // [B][NPOINT][NSLOT]
{
#pragma clang fp contract(off)
    __shared__ unsigned long long s_res[2];        // winner key, dbuf

    const int blk = blockIdx.x;
    const int b = blk & (BATCH - 1);          // batch -> XCD (round-robin)
    const int k = blk >> 3;                   // sub-block within batch
    const int t = threadIdx.x;
    const int w = t >> 6;                     // wave id
    const int l = t & 63;                     // lane id

    const float* __restrict__ px = pts_t + (size_t)b * 3 * N;
    const float* __restrict__ py = px + N;
    const float* __restrict__ pz = py + N;
    const f2* __restrict__ px2 = (const f2*)px;
    const f2* __restrict__ py2 = (const f2*)py;
    const f2* __restrict__ pz2 = (const f2*)pz;
    float* outx = out + (size_t)b * 3 * NPOINT;
    float* outy = outx + NPOINT;
    float* outz = outy + NPOINT;

    unsigned long long* __restrict__ slotb =
        gslot + (size_t)b * NPOINT * NSLOT;

    // ---- all point state in registers: 8 f2 per array (16 pts/thread) ----
#define DECL(g) f2 x##g, y##g, z##g, T##g;
    REP8(DECL)
#undef DECL

#define LOADG(g) { const int q = k * QB + (g) * NT + t;           \
                   x##g = px2[q]; y##g = py2[q]; z##g = pz2[q];   \
                   T##g = (f2){1e10f, 1e10f}; }
    REP8(LOADG)
#undef LOADG

    // First selected index is 0 (reference: idx[0] = 0).
    float lx = px[0], ly = py[0], lz = pz[0];
    if (k == 0 && t == 0) { outx[0] = lx; outy[0] = ly; outz[0] = lz; }
    __syncthreads();

    for (int j = 1; j < NPOINT; ++j) {
        const f2 lx2 = (f2){lx, lx};
        const f2 ly2 = (f2){ly, ly};
        const f2 lz2 = (f2){lz, lz};

        // --- update temps vs pivot; per-lane running max (pure VALU) ---
        f2 mx = (f2){0.0f, 0.0f};
#define UPD(g) { f2 dz = z##g - lz2;                                     \
                 f2 dx = x##g - lx2;                                     \
                 f2 dy = y##g - ly2;                                     \
                 f2 s  = (dx * dx + dy * dy) + dz * dz; /* numpy order */\
                 T##g.x = fminf(T##g.x, s.x);                            \
                 T##g.y = fminf(T##g.y, s.y);                            \
                 mx.x = fmaxf(mx.x, T##g.x);                             \
                 mx.y = fmaxf(mx.y, T##g.y); }
        REP8(UPD)
#undef UPD
        const float vlane = fmaxf(mx.x, mx.y);   // lane-local max (>= 0)

        // --- lane-local argmax (lowest original idx achieving vlane) ---
        int cand = N;
#define SCANG(g) { const int q = k * QB + (g) * NT + t;           \
                   cand = (T##g.y == vlane) ? 2 * q + 1 : cand;   \
                   cand = (T##g.x == vlane) ? 2 * q     : cand; }
        REP8R(SCANG)                       // descending -> lowest idx wins
#undef SCANG

        // --- wave max via DPP (uint domain; values >= 0) ---
        const unsigned vbits = __float_as_uint(vlane);
        const unsigned Mbits = wave_umax(vbits);
        // tie-break: max of (N - cand) over lanes matching Mbits (>=1 exists)
        const unsigned uidx  = wave_umax(vbits == Mbits ? (unsigned)(N - cand)
                                                        : 0u);
        const unsigned long long key =
            ((unsigned long long)Mbits << 32) | uidx;

        // --- publish this wave's key immediately (no barrier, no LDS) ---
        unsigned long long* __restrict__ slots = slotb + (size_t)j * NSLOT;
        if (l == 0)
            __hip_atomic_store(&slots[k * NW + w], key, __ATOMIC_RELAXED,
                               __HIP_MEMORY_SCOPE_AGENT);

        // --- wave 0 only: poll all 32 slots (lanes 0..31, 4 lines) ---
        if (w == 0) {
            unsigned long long o = 0ull;
            if (l < NSLOT) {
                do {
                    o = __hip_atomic_load(&slots[l], __ATOMIC_RELAXED,
                                          __HIP_MEMORY_SCOPE_AGENT);
                } while (o == 0ull);
            }
            QP_U64MAX(o, 0xB1);   // quad_perm [1,0,3,2]: xor 1
            QP_U64MAX(o, 0x4E);   // quad_perm [2,3,0,1]: xor 2
            // lanes 0,4,8,...,28 hold their quad's max; scalar tree
            unsigned long long K = rdlane_u64(o, 0);
#pragma unroll
            for (int q = 4; q < NSLOT; q += 4) {
                const unsigned long long m = rdlane_u64(o, q);
                K = m > K ? m : K;
            }
            if (l == 0) s_res[j & 1] = K;
        }
        __syncthreads();                       // the only barrier per iter

        const unsigned long long K = s_res[j & 1];
        const int sel =
            __builtin_amdgcn_readfirstlane(N - (int)(unsigned)(K & 0xffffffffu));
        lx = px[sel];                      // uniform -> scalar load (L2-hit)
        ly = py[sel];
        lz = pz[sel];
        if (k == 0 && t == 0) { outx[j] = lx; outy[j] = ly; outz[j] = lz; }
    }
}

extern "C" void kernel_launch(void* const* d_in, const int* in_sizes, int n_in,
                              void* d_out, int out_size, void* d_ws, size_t ws_size,
                              hipStream_t stream) {
    // d_in[0]: points_xyz (B,N,3) — unused
    // d_in[1]: points_xyz_t (B,3,N)
    // d_in[2]: features_with_xyz (B,67,N) — unused
    // d_ws: gslot u64[B][NPOINT][NSLOT] = 4 MiB, zeroed per launch
    const float* pts_t = (const float*)d_in[1];
    float* out = (float*)d_out;
    unsigned long long* gslot = (unsigned long long*)d_ws;
    hipMemsetAsync(d_ws, 0,
                   (size_t)BATCH * NPOINT * NSLOT * sizeof(unsigned long long),
                   stream);
    fps_kernel<<<NBLK, NT, 0, stream>>>(pts_t, out, gslot);
}

// Round 13
// 2705.261 us; speedup vs baseline: 1.5530x; 1.5530x over previous
//
#include <hip/hip_runtime.h>

#define BATCH 8
#define KSPLIT 8                       // blocks (CUs) per batch
#define NBLK (BATCH * KSPLIT)          // 64 blocks, 1 per CU, all co-resident
#define N 32768
#define NPOINT 2048
#define NT 256                         // threads per block (4 waves = 1/SIMD)
#define NW (NT / 64)                   // 4 waves
#define QB (N / 2 / KSPLIT)            // f2 elems per block = 2048

typedef __attribute__((ext_vector_type(2))) float f2;

// Multi-CU FPS, round-12: r10's proven global exchange (1 key/block, 8 slots
// = ONE cache line per batch, wave-0-only pollers), with ALL intra-block
// barriers replaced by j-indexed LDS data-rides-the-flag spins:
//   waves 1-3: ds_write key -> s_wkey[j][w-1]; spin s_res[j] != 0 -> sel
//   wave 0:    lanes 0-2 spin peer keys (lane 3 = own), quad-perm reduce,
//              publish block key (relaxed agent store), poll 8 global slots
//              (lanes 0-7, one 64B line), reduce, ds_write s_res[j]
// Zero __syncthreads in the main loop; LDS slots zeroed once at startup.
// Key = (dist_bits<<32 | N-idx) != 0 always; max dist, lowest original
// index on ties (dist >= 0 -> float bits monotone as unsigned).
// Bit-exact numpy semantics: contract off, (xx+yy)+zz order, no FMA.

#define REP8(M)  M(0) M(1) M(2) M(3) M(4) M(5) M(6) M(7)
#define REP8R(M) M(7) M(6) M(5) M(4) M(3) M(2) M(1) M(0)

// one DPP max step: v = max(v, dpp_shift(v)), invalid lanes contribute 0
#define DPP_UMAX(v, ctrl) {                                                  \
    unsigned _t = (unsigned)__builtin_amdgcn_update_dpp(                     \
        0, (int)(v), (ctrl), 0xf, 0xf, true);                                \
    (v) = (v) > _t ? (v) : _t; }

// full wave-64 max of nonneg uint, result uniform via readlane 63
__device__ __forceinline__ unsigned wave_umax(unsigned v) {
    DPP_UMAX(v, 0x111);   // row_shr:1
    DPP_UMAX(v, 0x112);   // row_shr:2
    DPP_UMAX(v, 0x114);   // row_shr:4
    DPP_UMAX(v, 0x118);   // row_shr:8
    DPP_UMAX(v, 0x142);   // row_bcast:15
    DPP_UMAX(v, 0x143);   // row_bcast:31
    return (unsigned)__builtin_amdgcn_readlane((int)v, 63);
}

// u64 max with quad_perm exchange, ctrl compile-time const
#define QP_U64MAX(v, ctrl) {                                                 \
    unsigned _lo = (unsigned)__builtin_amdgcn_update_dpp(                    \
        0, (int)(unsigned)(v), (ctrl), 0xf, 0xf, false);                     \
    unsigned _hi = (unsigned)__builtin_amdgcn_update_dpp(                    \
        0, (int)(unsigned)((v) >> 32), (ctrl), 0xf, 0xf, false);             \
    unsigned long long _p = ((unsigned long long)_hi << 32) | _lo;           \
    (v) = _p > (v) ? _p : (v); }

__device__ __forceinline__ unsigned long long rdlane_u64(unsigned long long v,
                                                         int lane) {
    const unsigned lo = (unsigned)__builtin_amdgcn_readlane(
        (int)(unsigned)v, lane);
    const unsigned hi = (unsigned)__builtin_amdgcn_readlane(
        (int)(unsigned)(v >> 32), lane);
    return ((unsigned long long)hi << 32) | lo;
}

__global__ __attribute__((amdgpu_flat_work_group_size(NT, NT),
                          amdgpu_waves_per_eu(2, 2)))
void fps_kernel(const float* __restrict__ pts_t,        // (B,3,N)
                float* __restrict__ out,                // (B,3,NPOINT)
                unsigned long long* __restrict__ gslot) // [B][NPOINT][KSPLIT]
{
#pragma clang fp contract(off)
    __shared__ unsigned long long s_wkey[NPOINT][3];   // 48 KiB, j-indexed
    __shared__ unsigned long long s_res[NPOINT];       // 16 KiB, j-indexed

    const int blk = blockIdx.x;
    const int b = blk & (BATCH - 1);          // batch -> XCD (round-robin)
    const int k = blk >> 3;                   // sub-block within batch
    const int t = threadIdx.x;
    const int w = t >> 6;                     // wave id
    const int l = t & 63;                     // lane id

    const float* __restrict__ px = pts_t + (size_t)b * 3 * N;
    const float* __restrict__ py = px + N;
    const float* __restrict__ pz = py + N;
    const f2* __restrict__ px2 = (const f2*)px;
    const f2* __restrict__ py2 = (const f2*)py;
    const f2* __restrict__ pz2 = (const f2*)pz;
    float* outx = out + (size_t)b * 3 * NPOINT;
    float* outy = outx + NPOINT;
    float* outz = outy + NPOINT;

    unsigned long long* __restrict__ slotb =
        gslot + (size_t)b * NPOINT * KSPLIT;

    // ---- all point state in registers: 8 f2 per array (16 pts/thread) ----
#define DECL(g) f2 x##g, y##g, z##g, T##g;
    REP8(DECL)
#undef DECL

#define LOADG(g) { const int q = k * QB + (g) * NT + t;           \
                   x##g = px2[q]; y##g = py2[q]; z##g = pz2[q];   \
                   T##g = (f2){1e10f, 1e10f}; }
    REP8(LOADG)
#undef LOADG

    // ---- zero the j-indexed LDS flag slots (LDS starts as garbage) ----
    {
        unsigned long long* s0 = &s_wkey[0][0];
        for (int i = t; i < NPOINT * 3; i += NT) s0[i] = 0ull;
        for (int i = t; i < NPOINT; i += NT) s_res[i] = 0ull;
    }

    // First selected index is 0 (reference: idx[0] = 0).
    float lx = px[0], ly = py[0], lz = pz[0];
    if (k == 0 && t == 0) { outx[0] = lx; outy[0] = ly; outz[0] = lz; }
    __syncthreads();                          // the ONLY barrier (startup)

    for (int j = 1; j < NPOINT; ++j) {
        const f2 lx2 = (f2){lx, lx};
        const f2 ly2 = (f2){ly, ly};
        const f2 lz2 = (f2){lz, lz};

        // --- update temps vs pivot; per-lane running max (pure VALU) ---
        f2 mx = (f2){0.0f, 0.0f};
#define UPD(g) { f2 dz = z##g - lz2;                                     \
                 f2 dx = x##g - lx2;                                     \
                 f2 dy = y##g - ly2;                                     \
                 f2 s  = (dx * dx + dy * dy) + dz * dz; /* numpy order */\
                 T##g.x = fminf(T##g.x, s.x);                            \
                 T##g.y = fminf(T##g.y, s.y);                            \
                 mx.x = fmaxf(mx.x, T##g.x);                             \
                 mx.y = fmaxf(mx.y, T##g.y); }
        REP8(UPD)
#undef UPD
        const float vlane = fmaxf(mx.x, mx.y);   // lane-local max (>= 0)

        // --- lane-local argmax (lowest original idx achieving vlane) ---
        int cand = N;
#define SCANG(g) { const int q = k * QB + (g) * NT + t;           \
                   cand = (T##g.y == vlane) ? 2 * q + 1 : cand;   \
                   cand = (T##g.x == vlane) ? 2 * q     : cand; }
        REP8R(SCANG)                       // descending -> lowest idx wins
#undef SCANG

        // --- wave max via DPP (uint domain; values >= 0) ---
        const unsigned vbits = __float_as_uint(vlane);
        const unsigned Mbits = wave_umax(vbits);
        // tie-break: max of (N - cand) over lanes matching Mbits (>=1 exists)
        const unsigned uidx  = wave_umax(vbits == Mbits ? (unsigned)(N - cand)
                                                        : 0u);
        const unsigned long long key =
            ((unsigned long long)Mbits << 32) | uidx;

        unsigned long long K;
        if (w > 0) {
            // --- publish wave key to LDS; spin on the iteration's result ---
            if (l == 0)
                __hip_atomic_store(&s_wkey[j][w - 1], key, __ATOMIC_RELAXED,
                                   __HIP_MEMORY_SCOPE_WORKGROUP);
            do {
                K = __hip_atomic_load(&s_res[j], __ATOMIC_RELAXED,
                                      __HIP_MEMORY_SCOPE_WORKGROUP);
            } while (K == 0ull);
        } else {
            // --- wave 0: gather 3 peer keys (lanes 0-2 spin) + own (l>=3) ---
            unsigned long long o = key;
            if (l < 3) {
                do {
                    o = __hip_atomic_load(&s_wkey[j][l], __ATOMIC_RELAXED,
                                          __HIP_MEMORY_SCOPE_WORKGROUP);
                } while (o == 0ull);
            }
            QP_U64MAX(o, 0xB1);   // quad_perm [1,0,3,2]
            QP_U64MAX(o, 0x4E);   // quad_perm [2,3,0,1]
            const unsigned long long bk = rdlane_u64(o, 0);  // block key

            // --- publish block key: one relaxed agent store ---
            unsigned long long* __restrict__ slots =
                slotb + (size_t)j * KSPLIT;
            if (l == 0)
                __hip_atomic_store(&slots[k], bk, __ATOMIC_RELAXED,
                                   __HIP_MEMORY_SCOPE_AGENT);

            // --- poll 8 global slots (lanes 0-7, one 64B line) ---
            unsigned long long g = 0ull;
            if (l < KSPLIT) {
                do {
                    g = __hip_atomic_load(&slots[l], __ATOMIC_RELAXED,
                                          __HIP_MEMORY_SCOPE_AGENT);
                } while (g == 0ull);
            }
            QP_U64MAX(g, 0xB1);
            QP_U64MAX(g, 0x4E);
            const unsigned long long m03 = rdlane_u64(g, 0);
            const unsigned long long m47 = rdlane_u64(g, 4);
            K = m47 > m03 ? m47 : m03;                       // uniform

            // --- release waves 1-3 ---
            if (l == 0)
                __hip_atomic_store(&s_res[j], K, __ATOMIC_RELAXED,
                                   __HIP_MEMORY_SCOPE_WORKGROUP);
        }

        const int sel =
            __builtin_amdgcn_readfirstlane(N - (int)(unsigned)(K & 0xffffffffu));
        lx = px[sel];                      // uniform -> scalar load (L2-hit)
        ly = py[sel];
        lz = pz[sel];
        if (k == 0 && t == 0) { outx[j] = lx; outy[j] = ly; outz[j] = lz; }
    }
}

extern "C" void kernel_launch(void* const* d_in, const int* in_sizes, int n_in,
                              void* d_out, int out_size, void* d_ws, size_t ws_size,
                              hipStream_t stream) {
    // d_in[0]: points_xyz (B,N,3) — unused
    // d_in[1]: points_xyz_t (B,3,N)
    // d_in[2]: features_with_xyz (B,67,N) — unused
    // d_ws: gslot u64[B][NPOINT][KSPLIT] = 1 MiB, zeroed per launch
    const float* pts_t = (const float*)d_in[1];
    float* out = (float*)d_out;
    unsigned long long* gslot = (unsigned long long*)d_ws;
    hipMemsetAsync(d_ws, 0,
                   (size_t)BATCH * NPOINT * KSPLIT * sizeof(unsigned long long),
                   stream);
    fps_kernel<<<NBLK, NT, 0, stream>>>(pts_t, out, gslot);
}